// Round 6
// baseline (618.380 us; speedup 1.0000x reference)
//
#include <hip/hip_runtime.h>
#include <hip/hip_bf16.h>
#include <math.h>

// ============================================================================
// SelfAttention B=4 S=4096 D=512, fp32 in/out, bf16 MFMA internally.
//
// R11: design UNDER the 128-VGPR wall instead of fighting it.
//  Evidence R7-R10: launch_bounds 2nd arg AND amdgpu_waves_per_eu are both
//  ignored; the allocator always budgets ~128 VGPR/wave (4 waves/EU).
//  R10 (live ~148) still spilled ~10 MB and lost R6's load pipelining.
//  R11 re-tiles so everything fits 128 spill-free:
//   - 32 q-rows/block, 512 blocks (= 2 blocks/CU at 65 KB LDS: for once the
//     compiler's 2-block assumption is TRUE -> 16 waves/CU latency hiding).
//   - wave owns 64 k-cols in QK (s4[2][4]=32 regs, ONE pass, K read once)
//     and 64 d-cols in PV (o[2][4]=32 regs).
//     Peak live ~110 (QK, compiler has slack to pipeline K loads)
//     / ~116 (PV, explicit 2-deep rolling V prefetch).
//   - DPP lane^1 pack -> 4B Ps writes (kills the 9-way write conflict).
//   - Lockstep 2-barrier/kt structure (R6-proven L2 behavior: barrier pacing
//     keeps all co-XCD blocks in the same K/V window -> L2-resident stream).
//  Cost accepted: 512 blocks x 8 MB = 4 GB L2 K/V traffic (~120 us at
//  per-XCD L2 BW), overlapped with the ~66 us MFMA floor.
//
// QKV projection (unchanged): fused M=16384,N=1536,K=512 GEMM, m97 structure,
// Q pre-scaled by log2e/sqrt(512), V written transposed.
// ============================================================================

typedef __bf16 bfx8 __attribute__((ext_vector_type(8)));
typedef __bf16 bfx4 __attribute__((ext_vector_type(4)));
typedef float  fx4  __attribute__((ext_vector_type(4)));

#define HID   512
#define NBATCH 4
#define SEQ   4096
#define MROWS (NBATCH * SEQ)
#define QROWS 32

#if __has_builtin(__builtin_amdgcn_exp2f)
#define EXPFN(x) __builtin_amdgcn_exp2f(x)
#define QSCALE 0.06375871589f   /* (1/sqrt(512)) * log2(e) */
#else
#define EXPFN(x) __expf(x)
#define QSCALE 0.04419417382f   /* 1/sqrt(512) */
#endif

constexpr int MODE_QKV = 0;  // C0=Q(bf16,scaled) C1=K(bf16) C2=Vt(bf16,transposed)
constexpr int MODE_EXP = 2;  // (not launched; kept for template completeness)
constexpr int MODE_DIV = 3;

// ---------------------------------------------------------------------------
__device__ __forceinline__ void gload_lds16(const __bf16* gsrc, __bf16* ldst) {
  __builtin_amdgcn_global_load_lds(
      (const __attribute__((address_space(1))) unsigned int*)gsrc,
      (__attribute__((address_space(3))) unsigned int*)ldst,
      16, 0, 0);
}

// ---------------------------------------------------------------------------
__global__ void prep_x_kernel(const float* __restrict__ X, __bf16* __restrict__ Xb) {
  int i = (blockIdx.x * 256 + threadIdx.x) * 4;
  const float4 v = *(const float4*)(X + i);
  bfx4 o;
  o[0] = (__bf16)v.x; o[1] = (__bf16)v.y; o[2] = (__bf16)v.z; o[3] = (__bf16)v.w;
  *(bfx4*)(Xb + i) = o;
}

__global__ void prep_w_kernel(const float* __restrict__ Wq, const float* __restrict__ Wk,
                              const float* __restrict__ Wv, __bf16* __restrict__ Wt) {
  int id  = blockIdx.x * 256 + threadIdx.x;   // 0 .. 3*512*512-1
  int g   = id >> 18;
  int rem = id & ((1 << 18) - 1);
  int i   = rem >> 9;          // input dim (row of W)
  int o   = rem & 511;         // output dim (col of W) -- coalesced read
  const float* W = (g == 0) ? Wq : ((g == 1) ? Wk : Wv);
  Wt[(g << 18) + (o << 9) + i] = (__bf16)W[rem];
}

// ---------------------------------------------------------------------------
// QKV GEMM (unchanged): C[M,N] = A[M,K] @ B[N,K]^T + bias epilogues.
template <int MODE, int TM, int TN>
__global__ __launch_bounds__(256)
void gemm_bt(const __bf16* __restrict__ A, const __bf16* __restrict__ B,
             void* __restrict__ C0v, void* __restrict__ C1v, void* __restrict__ C2v,
             const float* __restrict__ b0, const float* __restrict__ b1,
             const float* __restrict__ b2, float* __restrict__ rowsum,
             int lda, int ldb, int ldc, int K_,
             long sA, long sB, long sC, int sR) {
  constexpr int MT = TM / 32;
  constexpr int NT = TN / 32;
  constexpr int ABE = (TM + TN) * 64;
  constexpr int CTE = (MODE == MODE_DIV) ? TM * TN * 2 : TM * TN;
  constexpr int LDSN = (ABE > CTE) ? ABE : CTE;
  __shared__ __bf16 L[LDSN];
  __bf16* As = L;
  __bf16* Bs = L + TM * 64;

  const int z = blockIdx.z;
  A += (long)z * sA;
  B += (long)z * sB;

  const int tid  = threadIdx.x;
  const int lane = tid & 63;
  const int w    = tid >> 6;
  const int wm   = w >> 1, wn = w & 1;
  const int lm   = lane & 15, lq = lane >> 4;

  const int row0 = blockIdx.y * TM;
  const int col0 = blockIdx.x * TN;

  const __bf16* Ag = A + (long)row0 * lda;
  const __bf16* Bg = B + (long)col0 * ldb;

  fx4 acc[MT][NT] = {};

  for (int kt = 0; kt < K_; kt += 64) {
    __syncthreads();
#pragma unroll
    for (int it = 0; it < TM / 32; ++it) {
      int s = it * 256 + tid;
      int r = s >> 3, c = ((s & 7) ^ (r & 7)) << 3;
      gload_lds16(Ag + (long)r * lda + kt + c, As + it * 2048 + w * 512);
    }
#pragma unroll
    for (int it = 0; it < TN / 32; ++it) {
      int s = it * 256 + tid;
      int r = s >> 3, c = ((s & 7) ^ (r & 7)) << 3;
      gload_lds16(Bg + (long)r * ldb + kt + c, Bs + it * 2048 + w * 512);
    }
    __syncthreads();
#pragma unroll
    for (int kk = 0; kk < 2; ++kk) {
      bfx8 af[MT], bfr[NT];
#pragma unroll
      for (int t = 0; t < MT; ++t) {
        int ra = wm * (TM / 2) + t * 16 + lm;
        af[t] = *(const bfx8*)(As + ra * 64 + (((kk * 4 + lq) ^ (ra & 7)) << 3));
      }
#pragma unroll
      for (int t = 0; t < NT; ++t) {
        int rb = wn * (TN / 2) + t * 16 + lm;
        bfr[t] = *(const bfx8*)(Bs + rb * 64 + (((kk * 4 + lq) ^ (rb & 7)) << 3));
      }
#pragma unroll
      for (int mt = 0; mt < MT; ++mt)
#pragma unroll
        for (int nt = 0; nt < NT; ++nt)
          acc[mt][nt] = __builtin_amdgcn_mfma_f32_16x16x32_bf16(af[mt], bfr[nt],
                                                                acc[mt][nt], 0, 0, 0);
    }
  }

  const int lr0 = wm * (TM / 2);
  const int lc0 = wn * (TN / 2);

  __syncthreads();

  if constexpr (MODE == MODE_QKV) {
    const int g   = col0 >> 9;
    const int gc  = col0 & 511;
    const float* bias = (g == 0) ? b0 : ((g == 1) ? b1 : b2);
    float bvv[NT];
#pragma unroll
    for (int nt = 0; nt < NT; ++nt) bvv[nt] = bias[gc + lc0 + nt * 16 + lm];

    if (g < 2) {  // Q (pre-scaled) / K: LDS C-tile roundtrip, vectorized store
      __bf16* Ct = L;
#pragma unroll
      for (int mt = 0; mt < MT; ++mt)
#pragma unroll
        for (int nt = 0; nt < NT; ++nt)
#pragma unroll
          for (int i = 0; i < 4; ++i) {
            float v = acc[mt][nt][i] + bvv[nt];
            if (g == 0) v *= QSCALE;
            Ct[(lr0 + mt * 16 + lq * 4 + i) * TN + lc0 + nt * 16 + lm] = (__bf16)v;
          }
      __syncthreads();
      __bf16* C = (g == 0) ? (__bf16*)C0v : (__bf16*)C1v;
#pragma unroll
      for (int j = 0; j < TM * TN / 2048; ++j) {
        int s = j * 256 + tid;
        int off = s * 8;
        int r = off / TN, c = off % TN;
        *(bfx8*)(C + (long)(row0 + r) * ldc + gc + c) = *(const bfx8*)(Ct + off);
      }
    } else {  // V, transposed: Vt[b][hid][seq]
      __bf16* C = (__bf16*)C2v;
#pragma unroll
      for (int mt = 0; mt < MT; ++mt)
#pragma unroll
        for (int nt = 0; nt < NT; ++nt) {
          int c  = gc + lc0 + nt * 16 + lm;
          int rb = row0 + lr0 + mt * 16 + lq * 4;
          int b  = rb >> 12;
          int s  = rb & 4095;
          bfx4 pk;
#pragma unroll
          for (int i = 0; i < 4; ++i) pk[i] = (__bf16)(acc[mt][nt][i] + bvv[nt]);
          *(bfx4*)(C + ((long)b * HID + c) * SEQ + s) = pk;
        }
    }
  } else if constexpr (MODE == MODE_EXP) {
    __bf16* Ct = L;
    float* rsump = rowsum + (long)z * sR;
#pragma unroll
    for (int mt = 0; mt < MT; ++mt)
#pragma unroll
      for (int i = 0; i < 4; ++i) {
        int rl = lr0 + mt * 16 + lq * 4 + i;
        float rs = 0.f;
#pragma unroll
        for (int nt = 0; nt < NT; ++nt) {
          float e = EXPFN(acc[mt][nt][i]);
          Ct[rl * TN + lc0 + nt * 16 + lm] = (__bf16)e;
          rs += e;
        }
        rs += __shfl_xor(rs, 1);
        rs += __shfl_xor(rs, 2);
        rs += __shfl_xor(rs, 4);
        rs += __shfl_xor(rs, 8);
        if (lm == 0) atomicAdd(&rsump[row0 + rl], rs);
      }
    __syncthreads();
    __bf16* C = ((__bf16*)C0v) + (long)z * sC;
#pragma unroll
    for (int j = 0; j < TM * TN / 2048; ++j) {
      int s = j * 256 + tid;
      int off = s * 8;
      int r = off / TN, c = off % TN;
      *(bfx8*)(C + (long)(row0 + r) * ldc + col0 + c) = *(const bfx8*)(Ct + off);
    }
  } else {  // MODE_DIV
    float* Cf = (float*)L;
    const float* rsump = rowsum + (long)z * sR;
#pragma unroll
    for (int mt = 0; mt < MT; ++mt)
#pragma unroll
      for (int i = 0; i < 4; ++i) {
        int rl = lr0 + mt * 16 + lq * 4 + i;
        float inv = 1.f / rsump[row0 + rl];
#pragma unroll
        for (int nt = 0; nt < NT; ++nt)
          Cf[rl * TN + lc0 + nt * 16 + lm] = acc[mt][nt][i] * inv;
      }
    __syncthreads();
    float* C = ((float*)C0v) + (long)z * sC;
#pragma unroll
    for (int j = 0; j < TM * TN / 1024; ++j) {
      int s = j * 256 + tid;
      int off = s * 4;
      int r = off / TN, c = off % TN;
      *(float4*)(C + (long)(row0 + r) * ldc + col0 + c) = *(const float4*)(Cf + off);
    }
  }
}

// ---------------------------------------------------------------------------
// Fused flash attention, lockstep, 32-q-row tiles, 2 blocks/CU.
// Block: 32 q-rows, 8 waves; wave w owns k-slice [w*64,+64) in QK and
// d-slice [w*64,+64) in PV. Per kt (512 k-rows):
//   QK: s4[2][4] over 16 d-steps (K-frags direct from L2, compiler-pipelined)
//   exp2 + rowsum + DPP-packed 4B Ps write; barrier;
//   PV: o[2][4] over 16 k-steps, 2-deep rolling V prefetch; barrier.
// Everything fits the 128-VGPR wall (peak live ~116) -> no scratch.
__global__ __launch_bounds__(512)
void flash_attn(const __bf16* __restrict__ Qg_, const __bf16* __restrict__ Kg_,
                const __bf16* __restrict__ Vg_, float* __restrict__ Og_) {
  __shared__ __bf16 Qs[QROWS * 512];   // 32 KB, chunk-XOR swizzled
  __shared__ __bf16 Ps[QROWS * 512];   // 32 KB, chunk-XOR swizzled
  __shared__ float  rsw[8 * QROWS];    // per-wave rowsum partials

  const int tid  = threadIdx.x;
  const int lane = tid & 63;
  const int w    = tid >> 6;        // wave 0..7
  const int lm   = lane & 15;
  const int lq   = lane >> 4;

  // XCD-bijective decode for 512 blocks: XCD x = bid&7, batch z = x>>1
  // (batch pinned to XCD pair), qb = (x&1)*64 + bid>>3  in 0..127.
  const int bid = blockIdx.x;
  const int x   = bid & 7;
  const int z   = x >> 1;
  const int qb  = ((x & 1) << 6) | (bid >> 3);
  const long q0 = (long)qb * QROWS;

  const __bf16* Qg = Qg_ + ((long)z * SEQ + q0) * HID;
  const __bf16* Kg = Kg_ + (long)z * SEQ * HID;
  const __bf16* Vg = Vg_ + (long)z * HID * SEQ;
  float*        Og = Og_ + ((long)z * SEQ + q0) * HID;

  // ---- stage Q tile (32x512) into LDS, swizzled, width-16 async ----
#pragma unroll
  for (int it = 0; it < 4; ++it) {
    int idx = it * 512 + tid;          // 16B chunk index, 2048 total
    int r   = idx >> 6;                // q-row 0..31
    int c6  = idx & 63;
    int src = (c6 & ~7) | ((c6 ^ r) & 7);
    gload_lds16(Qg + (long)r * HID + src * 8, Qs + (it * 512 + w * 64) * 8);
  }

  fx4 o[2][4]  = {};   // O slice: rows 0..31 x cols [w*64, w*64+64)
  fx4 rs4[2]   = {};   // rowsum partials rs4[mt][i]

  const __bf16* kp = Kg + (long)(w * 64 + lm) * HID + lq * 8;
  const __bf16* vp = Vg + (long)(w * 64 + lm) * SEQ + lq * 8;

  __syncthreads();   // Qs ready (drains global_load_lds)

  for (int kt = 0; kt < 8; ++kt) {
    // ---- QK: S[32q][64k-slice] over d=512, one pass ----
    fx4 s4[2][4] = {};
#pragma unroll
    for (int ds = 0; ds < 16; ++ds) {
      bfx8 bk[4];
#pragma unroll
      for (int nt = 0; nt < 4; ++nt)
        bk[nt] = *(const bfx8*)(kp + (long)nt * (16 * HID) + ds * 32);
      __builtin_amdgcn_s_setprio(1);
#pragma unroll
      for (int mt = 0; mt < 2; ++mt) {
        const int r = mt * 16 + lm;
        bfx8 af = *(const bfx8*)(Qs + r * 512 + ((ds >> 1) << 6) +
                   (((((ds & 1) << 2) + lq) ^ (r & 7)) << 3));
#pragma unroll
        for (int nt = 0; nt < 4; ++nt)
          s4[mt][nt] = __builtin_amdgcn_mfma_f32_16x16x32_bf16(
                           af, bk[nt], s4[mt][nt], 0, 0, 0);
      }
      __builtin_amdgcn_s_setprio(0);
    }
    kp += (long)512 * HID;

    // ---- exp2 + rowsum + DPP lane^1 pack -> 4B Ps writes (even lanes) ----
#pragma unroll
    for (int mt = 0; mt < 2; ++mt)
#pragma unroll
      for (int i = 0; i < 4; ++i) {
        const int r = mt * 16 + lq * 4 + i;
#pragma unroll
        for (int nt = 0; nt < 4; ++nt) {
          float e = EXPFN(s4[mt][nt][i]);   // Q pre-scaled: acc = score*log2e
          rs4[mt][i] += e;
          float en = __uint_as_float((unsigned)__builtin_amdgcn_mov_dpp(
                         (int)__float_as_uint(e), 0xB1, 0xF, 0xF, true));
          if (!(lm & 1)) {
            const int c = w * 64 + nt * 16 + lm;   // even
            union { __bf16 b[2]; unsigned u; } pk;
            pk.b[0] = (__bf16)e; pk.b[1] = (__bf16)en;
            *(unsigned*)(Ps + r * 512 +
                ((((c >> 3) ^ (r & 7)) << 3) | (c & 7))) = pk.u;
          }
        }
      }
    __syncthreads();   // Ps ready for all waves

    // ---- PV: O[32q][64d-slice] += P . V, rolling 2-deep V prefetch ----
    {
      bfx8 bvA[4], bvB[4];
#pragma unroll
      for (int nt = 0; nt < 4; ++nt)
        bvA[nt] = *(const bfx8*)(vp + (long)nt * (16 * SEQ));
#pragma unroll
      for (int g = 0; g < 8; ++g) {
        // step 2g (consume bvA, prefetch bvB)
#pragma unroll
        for (int nt = 0; nt < 4; ++nt)
          bvB[nt] = *(const bfx8*)(vp + (long)nt * (16 * SEQ) + (2 * g + 1) * 32);
        __builtin_amdgcn_s_setprio(1);
#pragma unroll
        for (int mt = 0; mt < 2; ++mt) {
          const int r = mt * 16 + lm;
          bfx8 pa = *(const bfx8*)(Ps + r * 512 +
                     ((((2 * g) * 4 + lq) ^ (r & 7)) << 3));
#pragma unroll
          for (int nt = 0; nt < 4; ++nt)
            o[mt][nt] = __builtin_amdgcn_mfma_f32_16x16x32_bf16(
                            pa, bvA[nt], o[mt][nt], 0, 0, 0);
        }
        __builtin_amdgcn_s_setprio(0);
        // step 2g+1 (consume bvB, prefetch bvA)
#pragma unroll
        for (int nt = 0; nt < 4; ++nt)
          if (g < 7)
            bvA[nt] = *(const bfx8*)(vp + (long)nt * (16 * SEQ) + (2 * g + 2) * 32);
        __builtin_amdgcn_s_setprio(1);
#pragma unroll
        for (int mt = 0; mt < 2; ++mt) {
          const int r = mt * 16 + lm;
          bfx8 pa = *(const bfx8*)(Ps + r * 512 +
                     ((((2 * g + 1) * 4 + lq) ^ (r & 7)) << 3));
#pragma unroll
          for (int nt = 0; nt < 4; ++nt)
            o[mt][nt] = __builtin_amdgcn_mfma_f32_16x16x32_bf16(
                            pa, bvB[nt], o[mt][nt], 0, 0, 0);
        }
        __builtin_amdgcn_s_setprio(0);
      }
      vp += 512;
    }
    __syncthreads();   // PV done reading Ps before next kt overwrites it
  }

  // ---- rowsum: reduce over the 16 column-lanes, then across waves ----
#pragma unroll
  for (int mt = 0; mt < 2; ++mt)
#pragma unroll
    for (int i = 0; i < 4; ++i) {
      float v = rs4[mt][i];
      v += __shfl_xor(v, 1);
      v += __shfl_xor(v, 2);
      v += __shfl_xor(v, 4);
      v += __shfl_xor(v, 8);
      if (lm == 0) rsw[w * QROWS + mt * 16 + lq * 4 + i] = v;
    }
  __syncthreads();

  // ---- divide + store ----
#pragma unroll
  for (int mt = 0; mt < 2; ++mt)
#pragma unroll
    for (int i = 0; i < 4; ++i) {
      const int r = mt * 16 + lq * 4 + i;
      float t = rsw[r];
#pragma unroll
      for (int ww = 1; ww < 8; ++ww) t += rsw[ww * QROWS + r];
      const float inv = 1.f / t;
#pragma unroll
      for (int nt = 0; nt < 4; ++nt)
        Og[(long)r * HID + w * 64 + nt * 16 + lm] = o[mt][nt][i] * inv;
    }
}

// ---------------------------------------------------------------------------
extern "C" void kernel_launch(void* const* d_in, const int* in_sizes, int n_in,
                              void* d_out, int out_size, void* d_ws, size_t ws_size,
                              hipStream_t stream) {
  (void)in_sizes; (void)n_in; (void)out_size; (void)ws_size;
  const float* X  = (const float*)d_in[0];
  const float* Wq = (const float*)d_in[1];
  const float* bq = (const float*)d_in[2];
  const float* Wk = (const float*)d_in[3];
  const float* bk = (const float*)d_in[4];
  const float* Wv = (const float*)d_in[5];
  const float* bv = (const float*)d_in[6];
  float* out = (float*)d_out;

  // workspace layout (bf16 elements): Xb, Wt, Q (pre-scaled), K, Vt  (~66 MB)
  __bf16* Xb = (__bf16*)d_ws;                  // 16384*512
  __bf16* Wt = Xb + (long)MROWS * HID;         // 3*512*512, [g][out][in]
  __bf16* Q  = Wt + 3 * HID * HID;             // 16384*512 (pre-scaled)
  __bf16* Kb = Q + (long)MROWS * HID;          // 16384*512
  __bf16* Vt = Kb + (long)MROWS * HID;         // [b][512][4096]

  prep_x_kernel<<<(MROWS * HID) / 1024, 256, 0, stream>>>(X, Xb);
  prep_w_kernel<<<(3 * HID * HID) / 256, 256, 0, stream>>>(Wq, Wk, Wv, Wt);

  // fused QKV projection: M=16384, N=1536, K=512
  gemm_bt<MODE_QKV, 128, 128><<<dim3(12, 128, 1), 256, 0, stream>>>(
      Xb, Wt, Q, Kb, Vt, bq, bk, bv, nullptr,
      HID, HID, HID, HID, 0, 0, 0, 0);

  // fused softmax(QK^T)V: 512 blocks (2/CU), 8 waves, 32-row Q-tiles
  flash_attn<<<dim3(512), 512, 0, stream>>>(Q, Kb, Vt, out);
}

// Round 8
// 457.530 us; speedup vs baseline: 1.3516x; 1.3516x over previous
//
#include <hip/hip_runtime.h>
#include <hip/hip_bf16.h>
#include <math.h>

// ============================================================================
// SelfAttention B=4 S=4096 D=512, fp32 in/out, bf16 MFMA internally.
//
// R13 == R12 resubmitted (R12 bench failed with GPUAcquisitionTimeout --
// infra, not kernel; source re-audited for ring races / swizzle algebra).
//
// R12: async-staged K + 16 waves -- remove the synchronous-L2 critical path.
//  R6-R11 unified diagnosis: every variant kept sync 200cy L2 loads feeding
//  MFMAs with only 2 waves/SIMD -> 11-20% MfmaUtil, and live-state >128 regs
//  made the allocator serialize the load pipeline (R6) or spill (R7-R10).
//  R12 aligns the design with both walls:
//   - 1024 threads = 16 waves = 4 waves/SIMD: matches the compiler's fixed
//     128-VGPR budget AND doubles TLP.
//   - K staged through a double-buffered LDS ring ([256k x 64d] 32KB chunks)
//     via async global_load_lds (m97 mechanism): staging of chunk c+1 (and
//     next kt's chunk 0, under exp+PV) overlaps compute of chunk c;
//     __syncthreads per chunk is the proven drain.
//   - Small wave tiles: QK s4[2][2]=16 regs (32q x 32k), PV o[2][4]=32 regs
//     (32q x 64d). Peak live ~110 -> spill-free WITH pipelining headroom.
//   - V direct from L2 with 2-deep rolling prefetch (hidden by 4 waves/SIMD).
//   - 64 q-rows/block, 256 blocks: K/V L2 stream stays 2 GB (R6-proven).
//  LDS: Qs 64KB + Ps[64x256] 32KB + Ks ring 2x32KB = 160KB exact;
//  rowsum scratch aliases the K-ring (dead after the last QK chunk).
//
// QKV projection (unchanged): fused M=16384,N=1536,K=512 GEMM, m97 structure,
// Q pre-scaled by log2e/sqrt(512), V written transposed.
// ============================================================================

typedef __bf16 bfx8 __attribute__((ext_vector_type(8)));
typedef __bf16 bfx4 __attribute__((ext_vector_type(4)));
typedef float  fx4  __attribute__((ext_vector_type(4)));

#define HID   512
#define NBATCH 4
#define SEQ   4096
#define MROWS (NBATCH * SEQ)

#if __has_builtin(__builtin_amdgcn_exp2f)
#define EXPFN(x) __builtin_amdgcn_exp2f(x)
#define QSCALE 0.06375871589f   /* (1/sqrt(512)) * log2(e) */
#else
#define EXPFN(x) __expf(x)
#define QSCALE 0.04419417382f   /* 1/sqrt(512) */
#endif

constexpr int MODE_QKV = 0;  // C0=Q(bf16,scaled) C1=K(bf16) C2=Vt(bf16,transposed)
constexpr int MODE_EXP = 2;  // (not launched; kept for template completeness)
constexpr int MODE_DIV = 3;

// ---------------------------------------------------------------------------
__device__ __forceinline__ void gload_lds16(const __bf16* gsrc, __bf16* ldst) {
  __builtin_amdgcn_global_load_lds(
      (const __attribute__((address_space(1))) unsigned int*)gsrc,
      (__attribute__((address_space(3))) unsigned int*)ldst,
      16, 0, 0);
}

// ---------------------------------------------------------------------------
__global__ void prep_x_kernel(const float* __restrict__ X, __bf16* __restrict__ Xb) {
  int i = (blockIdx.x * 256 + threadIdx.x) * 4;
  const float4 v = *(const float4*)(X + i);
  bfx4 o;
  o[0] = (__bf16)v.x; o[1] = (__bf16)v.y; o[2] = (__bf16)v.z; o[3] = (__bf16)v.w;
  *(bfx4*)(Xb + i) = o;
}

__global__ void prep_w_kernel(const float* __restrict__ Wq, const float* __restrict__ Wk,
                              const float* __restrict__ Wv, __bf16* __restrict__ Wt) {
  int id  = blockIdx.x * 256 + threadIdx.x;   // 0 .. 3*512*512-1
  int g   = id >> 18;
  int rem = id & ((1 << 18) - 1);
  int i   = rem >> 9;          // input dim (row of W)
  int o   = rem & 511;         // output dim (col of W) -- coalesced read
  const float* W = (g == 0) ? Wq : ((g == 1) ? Wk : Wv);
  Wt[(g << 18) + (o << 9) + i] = (__bf16)W[rem];
}

// ---------------------------------------------------------------------------
// QKV GEMM (unchanged): C[M,N] = A[M,K] @ B[N,K]^T + bias epilogues.
template <int MODE, int TM, int TN>
__global__ __launch_bounds__(256)
void gemm_bt(const __bf16* __restrict__ A, const __bf16* __restrict__ B,
             void* __restrict__ C0v, void* __restrict__ C1v, void* __restrict__ C2v,
             const float* __restrict__ b0, const float* __restrict__ b1,
             const float* __restrict__ b2, float* __restrict__ rowsum,
             int lda, int ldb, int ldc, int K_,
             long sA, long sB, long sC, int sR) {
  constexpr int MT = TM / 32;
  constexpr int NT = TN / 32;
  constexpr int ABE = (TM + TN) * 64;
  constexpr int CTE = (MODE == MODE_DIV) ? TM * TN * 2 : TM * TN;
  constexpr int LDSN = (ABE > CTE) ? ABE : CTE;
  __shared__ __bf16 L[LDSN];
  __bf16* As = L;
  __bf16* Bs = L + TM * 64;

  const int z = blockIdx.z;
  A += (long)z * sA;
  B += (long)z * sB;

  const int tid  = threadIdx.x;
  const int lane = tid & 63;
  const int w    = tid >> 6;
  const int wm   = w >> 1, wn = w & 1;
  const int lm   = lane & 15, lq = lane >> 4;

  const int row0 = blockIdx.y * TM;
  const int col0 = blockIdx.x * TN;

  const __bf16* Ag = A + (long)row0 * lda;
  const __bf16* Bg = B + (long)col0 * ldb;

  fx4 acc[MT][NT] = {};

  for (int kt = 0; kt < K_; kt += 64) {
    __syncthreads();
#pragma unroll
    for (int it = 0; it < TM / 32; ++it) {
      int s = it * 256 + tid;
      int r = s >> 3, c = ((s & 7) ^ (r & 7)) << 3;
      gload_lds16(Ag + (long)r * lda + kt + c, As + it * 2048 + w * 512);
    }
#pragma unroll
    for (int it = 0; it < TN / 32; ++it) {
      int s = it * 256 + tid;
      int r = s >> 3, c = ((s & 7) ^ (r & 7)) << 3;
      gload_lds16(Bg + (long)r * ldb + kt + c, Bs + it * 2048 + w * 512);
    }
    __syncthreads();
#pragma unroll
    for (int kk = 0; kk < 2; ++kk) {
      bfx8 af[MT], bfr[NT];
#pragma unroll
      for (int t = 0; t < MT; ++t) {
        int ra = wm * (TM / 2) + t * 16 + lm;
        af[t] = *(const bfx8*)(As + ra * 64 + (((kk * 4 + lq) ^ (ra & 7)) << 3));
      }
#pragma unroll
      for (int t = 0; t < NT; ++t) {
        int rb = wn * (TN / 2) + t * 16 + lm;
        bfr[t] = *(const bfx8*)(Bs + rb * 64 + (((kk * 4 + lq) ^ (rb & 7)) << 3));
      }
#pragma unroll
      for (int mt = 0; mt < MT; ++mt)
#pragma unroll
        for (int nt = 0; nt < NT; ++nt)
          acc[mt][nt] = __builtin_amdgcn_mfma_f32_16x16x32_bf16(af[mt], bfr[nt],
                                                                acc[mt][nt], 0, 0, 0);
    }
  }

  const int lr0 = wm * (TM / 2);
  const int lc0 = wn * (TN / 2);

  __syncthreads();

  if constexpr (MODE == MODE_QKV) {
    const int g   = col0 >> 9;
    const int gc  = col0 & 511;
    const float* bias = (g == 0) ? b0 : ((g == 1) ? b1 : b2);
    float bvv[NT];
#pragma unroll
    for (int nt = 0; nt < NT; ++nt) bvv[nt] = bias[gc + lc0 + nt * 16 + lm];

    if (g < 2) {  // Q (pre-scaled) / K: LDS C-tile roundtrip, vectorized store
      __bf16* Ct = L;
#pragma unroll
      for (int mt = 0; mt < MT; ++mt)
#pragma unroll
        for (int nt = 0; nt < NT; ++nt)
#pragma unroll
          for (int i = 0; i < 4; ++i) {
            float v = acc[mt][nt][i] + bvv[nt];
            if (g == 0) v *= QSCALE;
            Ct[(lr0 + mt * 16 + lq * 4 + i) * TN + lc0 + nt * 16 + lm] = (__bf16)v;
          }
      __syncthreads();
      __bf16* C = (g == 0) ? (__bf16*)C0v : (__bf16*)C1v;
#pragma unroll
      for (int j = 0; j < TM * TN / 2048; ++j) {
        int s = j * 256 + tid;
        int off = s * 8;
        int r = off / TN, c = off % TN;
        *(bfx8*)(C + (long)(row0 + r) * ldc + gc + c) = *(const bfx8*)(Ct + off);
      }
    } else {  // V, transposed: Vt[b][hid][seq]
      __bf16* C = (__bf16*)C2v;
#pragma unroll
      for (int mt = 0; mt < MT; ++mt)
#pragma unroll
        for (int nt = 0; nt < NT; ++nt) {
          int c  = gc + lc0 + nt * 16 + lm;
          int rb = row0 + lr0 + mt * 16 + lq * 4;
          int b  = rb >> 12;
          int s  = rb & 4095;
          bfx4 pk;
#pragma unroll
          for (int i = 0; i < 4; ++i) pk[i] = (__bf16)(acc[mt][nt][i] + bvv[nt]);
          *(bfx4*)(C + ((long)b * HID + c) * SEQ + s) = pk;
        }
    }
  } else if constexpr (MODE == MODE_EXP) {
    __bf16* Ct = L;
    float* rsump = rowsum + (long)z * sR;
#pragma unroll
    for (int mt = 0; mt < MT; ++mt)
#pragma unroll
      for (int i = 0; i < 4; ++i) {
        int rl = lr0 + mt * 16 + lq * 4 + i;
        float rs = 0.f;
#pragma unroll
        for (int nt = 0; nt < NT; ++nt) {
          float e = EXPFN(acc[mt][nt][i]);
          Ct[rl * TN + lc0 + nt * 16 + lm] = (__bf16)e;
          rs += e;
        }
        rs += __shfl_xor(rs, 1);
        rs += __shfl_xor(rs, 2);
        rs += __shfl_xor(rs, 4);
        rs += __shfl_xor(rs, 8);
        if (lm == 0) atomicAdd(&rsump[row0 + rl], rs);
      }
    __syncthreads();
    __bf16* C = ((__bf16*)C0v) + (long)z * sC;
#pragma unroll
    for (int j = 0; j < TM * TN / 2048; ++j) {
      int s = j * 256 + tid;
      int off = s * 8;
      int r = off / TN, c = off % TN;
      *(bfx8*)(C + (long)(row0 + r) * ldc + col0 + c) = *(const bfx8*)(Ct + off);
    }
  } else {  // MODE_DIV
    float* Cf = (float*)L;
    const float* rsump = rowsum + (long)z * sR;
#pragma unroll
    for (int mt = 0; mt < MT; ++mt)
#pragma unroll
      for (int i = 0; i < 4; ++i) {
        int rl = lr0 + mt * 16 + lq * 4 + i;
        float inv = 1.f / rsump[row0 + rl];
#pragma unroll
        for (int nt = 0; nt < NT; ++nt)
          Cf[rl * TN + lc0 + nt * 16 + lm] = acc[mt][nt][i] * inv;
      }
    __syncthreads();
    float* C = ((float*)C0v) + (long)z * sC;
#pragma unroll
    for (int j = 0; j < TM * TN / 1024; ++j) {
      int s = j * 256 + tid;
      int off = s * 4;
      int r = off / TN, c = off % TN;
      *(float4*)(C + (long)(row0 + r) * ldc + col0 + c) = *(const float4*)(Cf + off);
    }
  }
}

// ---------------------------------------------------------------------------
// Stage one K chunk [256 k-rows x 64 d] (32 KB) into Ks[BUF], pre-swizzled
// source so LDS chunk c8 of row kr holds global d-chunk (c8 ^ (kr&7)).
// 1024 threads x 2 issues of 16B. Dest is lane-linear (wave-uniform rule).
#define STAGEK(BUF, KTT, CC)                                                   \
  {                                                                            \
    _Pragma("unroll")                                                          \
    for (int it_ = 0; it_ < 2; ++it_) {                                        \
      int idx_ = it_ * 1024 + tid;                                             \
      int kr_  = idx_ >> 3;                                                    \
      int c8_  = idx_ & 7;                                                     \
      int sc_  = c8_ ^ (kr_ & 7);                                              \
      gload_lds16(Kg + ((long)(KTT) * 256 + kr_) * HID + (CC) * 64 + sc_ * 8,  \
                  &Ks[BUF][idx_ * 8]);                                         \
    }                                                                          \
  }

// Fused flash attention, 16 waves, async K-staging.
// Block: 64 q-rows, 1024 threads. kt loop: 16 x 256-k tiles.
//  QK: wave (qh=w>>3, kq=w&7) computes S[qh*32+32q][kq*32+32k]; d streamed
//      in 8 chunks of 64d from the Ks ring (double-buffered global_load_lds).
//  exp2 + rowsum(reg) + DPP-packed 4B writes into Ps[64x256].
//  PV: wave (qh, dq=w&7): O[qh*32+32q][dq*64+64d] += P.V, V direct from L2
//      with 2-deep rolling prefetch.
__global__ __launch_bounds__(1024)
void flash_attn(const __bf16* __restrict__ Qg_, const __bf16* __restrict__ Kg_,
                const __bf16* __restrict__ Vg_, float* __restrict__ Og_) {
  __shared__ __bf16 Qs[64 * 512];        // 64 KB, chunk-XOR swizzled
  __shared__ __bf16 Ps[64 * 256];        // 32 KB, chunk-XOR swizzled
  __shared__ __bf16 Ks[2][256 * 64];     // 64 KB K ring (async-staged)
  float* rsw = (float*)Ks;               // 16 waves x 32 rows, aliased (dead K)

  const int tid  = threadIdx.x;
  const int lane = tid & 63;
  const int w    = tid >> 6;        // wave 0..15
  const int lm   = lane & 15;
  const int lq   = lane >> 4;
  const int qh   = w >> 3;          // q-half (0/1): rows qh*32 .. +32
  const int u    = w & 7;           // QK: k-slice id; PV: d-slice id

  // XCD-bijective decode (256 blocks): XCD = bid&7; batch z = XCD pair.
  const int bid = blockIdx.x;
  const int z   = (bid & 7) >> 1;
  const int qb  = ((bid & 1) << 5) | (bid >> 3);   // 0..63
  const long q0 = (long)qb * 64;

  const __bf16* Qg = Qg_ + ((long)z * SEQ + q0) * HID;
  const __bf16* Kg = Kg_ + (long)z * SEQ * HID;
  const __bf16* Vg = Vg_ + (long)z * HID * SEQ;
  float*        Og = Og_ + ((long)z * SEQ + q0) * HID;

  // ---- stage Q tile (64x512) into LDS, swizzled, width-16 async ----
#pragma unroll
  for (int it = 0; it < 4; ++it) {
    int idx = it * 1024 + tid;         // 16B chunk index, 4096 total
    int r   = idx >> 6;
    int c6  = idx & 63;
    int src = (c6 & ~7) | ((c6 ^ r) & 7);
    gload_lds16(Qg + (long)r * HID + src * 8, Qs + idx * 8);
  }
  // stage first K chunk (kt=0, c=0) into ring buf 0
  STAGEK(0, 0, 0)

  fx4 o[2][4] = {};    // PV acc: rows qh*32+[0..32) x cols u*64+[0..64)
  fx4 rs4[2]  = {};    // rowsum partials (this wave's 32 k-cols, 32 q-rows)

  const __bf16* vp = Vg + (long)(u * 64 + lm) * SEQ + lq * 8;

  __syncthreads();     // Qs + K(0,0) ready (drains all global_load_lds)

  for (int kt = 0; kt < 16; ++kt) {
    // ---------- QK: S[32q x 32k] over d=512 in 8 chunks of 64d ----------
    fx4 s4[2][2] = {};
#pragma unroll
    for (int c = 0; c < 8; ++c) {
      if (c < 7) {
        STAGEK((c + 1) & 1, kt, c + 1)       // async next chunk
      } else if (kt < 15) {
        STAGEK(0, kt + 1, 0)                 // next kt's chunk 0 (under exp+PV)
      }
      const __bf16* Kb = Ks[c & 1];
#pragma unroll
      for (int dd = 0; dd < 2; ++dd) {       // two 32-d MFMA steps per chunk
        bfx8 bk[2];
#pragma unroll
        for (int kti = 0; kti < 2; ++kti) {
          const int kr = u * 32 + kti * 16 + lm;
          bk[kti] = *(const bfx8*)(Kb + kr * 64 + (((dd * 4 + lq) ^ (kr & 7)) << 3));
        }
        __builtin_amdgcn_s_setprio(1);
#pragma unroll
        for (int mt = 0; mt < 2; ++mt) {
          const int r  = qh * 32 + mt * 16 + lm;
          const int ds = c * 2 + dd;
          bfx8 af = *(const bfx8*)(Qs + r * 512 + ((ds >> 1) << 6) +
                     (((((ds & 1) << 2) + lq) ^ (r & 7)) << 3));
#pragma unroll
          for (int kti = 0; kti < 2; ++kti)
            s4[mt][kti] = __builtin_amdgcn_mfma_f32_16x16x32_bf16(
                              af, bk[kti], s4[mt][kti], 0, 0, 0);
        }
        __builtin_amdgcn_s_setprio(0);
      }
      if (c < 7) __syncthreads();  // next chunk staged + buf reuse safe
    }

    // ---------- exp2 + rowsum + DPP lane^1 pack -> 4B Ps writes ----------
#pragma unroll
    for (int mt = 0; mt < 2; ++mt)
#pragma unroll
      for (int i = 0; i < 4; ++i) {
        const int r = qh * 32 + mt * 16 + lq * 4 + i;
#pragma unroll
        for (int kti = 0; kti < 2; ++kti) {
          float e = EXPFN(s4[mt][kti][i]);   // Q pre-scaled: acc = score*log2e
          rs4[mt][i] += e;
          float en = __uint_as_float((unsigned)__builtin_amdgcn_mov_dpp(
                         (int)__float_as_uint(e), 0xB1, 0xF, 0xF, true));
          if (!(lm & 1)) {
            const int cc = u * 32 + kti * 16 + lm;   // even
            union { __bf16 b[2]; unsigned u32; } pk;
            pk.b[0] = (__bf16)e; pk.b[1] = (__bf16)en;
            *(unsigned*)(Ps + r * 256 +
                ((((cc >> 3) ^ (r & 7)) << 3) | (cc & 7))) = pk.u32;
          }
        }
      }
    __syncthreads();   // Ps ready for all waves

    // ---------- PV: O[32q x 64d] += P . V, rolling 2-deep V prefetch ------
    {
      bfx8 bvA[4], bvB[4];
#pragma unroll
      for (int nt = 0; nt < 4; ++nt)
        bvA[nt] = *(const bfx8*)(vp + (long)nt * (16 * SEQ));
#pragma unroll
      for (int g = 0; g < 4; ++g) {
        // step 2g: consume bvA, prefetch bvB
#pragma unroll
        for (int nt = 0; nt < 4; ++nt)
          bvB[nt] = *(const bfx8*)(vp + (long)nt * (16 * SEQ) + (2 * g + 1) * 32);
        __builtin_amdgcn_s_setprio(1);
#pragma unroll
        for (int mt = 0; mt < 2; ++mt) {
          const int r = qh * 32 + mt * 16 + lm;
          bfx8 pa = *(const bfx8*)(Ps + r * 256 +
                     ((((2 * g) * 4 + lq) ^ (r & 7)) << 3));
#pragma unroll
          for (int nt = 0; nt < 4; ++nt)
            o[mt][nt] = __builtin_amdgcn_mfma_f32_16x16x32_bf16(
                            pa, bvA[nt], o[mt][nt], 0, 0, 0);
        }
        __builtin_amdgcn_s_setprio(0);
        // step 2g+1: consume bvB, prefetch bvA
#pragma unroll
        for (int nt = 0; nt < 4; ++nt)
          if (g < 3)
            bvA[nt] = *(const bfx8*)(vp + (long)nt * (16 * SEQ) + (2 * g + 2) * 32);
        __builtin_amdgcn_s_setprio(1);
#pragma unroll
        for (int mt = 0; mt < 2; ++mt) {
          const int r = qh * 32 + mt * 16 + lm;
          bfx8 pa = *(const bfx8*)(Ps + r * 256 +
                     ((((2 * g + 1) * 4 + lq) ^ (r & 7)) << 3));
#pragma unroll
          for (int nt = 0; nt < 4; ++nt)
            o[mt][nt] = __builtin_amdgcn_mfma_f32_16x16x32_bf16(
                            pa, bvB[nt], o[mt][nt], 0, 0, 0);
        }
        __builtin_amdgcn_s_setprio(0);
      }
      vp += 256;
    }
    __syncthreads();   // PV done reading Ps; next-kt K(0) staged & drained
  }

  // ---- rowsum: reduce over 16 column-lanes -> rsw[w][32 rows] ----
#pragma unroll
  for (int mt = 0; mt < 2; ++mt)
#pragma unroll
    for (int i = 0; i < 4; ++i) {
      float v = rs4[mt][i];
      v += __shfl_xor(v, 1);
      v += __shfl_xor(v, 2);
      v += __shfl_xor(v, 4);
      v += __shfl_xor(v, 8);
      if (lm == 0) rsw[w * 32 + mt * 16 + lq * 4 + i] = v;
    }
  __syncthreads();

  // ---- divide + store (each wave stores its (qh, u) O slice) ----
#pragma unroll
  for (int mt = 0; mt < 2; ++mt)
#pragma unroll
    for (int i = 0; i < 4; ++i) {
      const int rl = mt * 16 + lq * 4 + i;          // row within the q-half
      const int r  = qh * 32 + rl;
      float t = 0.f;
#pragma unroll
      for (int kq = 0; kq < 8; ++kq) t += rsw[(qh * 8 + kq) * 32 + rl];
      const float inv = 1.f / t;
#pragma unroll
      for (int nt = 0; nt < 4; ++nt)
        Og[(long)r * HID + u * 64 + nt * 16 + lm] = o[mt][nt][i] * inv;
    }
}

// ---------------------------------------------------------------------------
extern "C" void kernel_launch(void* const* d_in, const int* in_sizes, int n_in,
                              void* d_out, int out_size, void* d_ws, size_t ws_size,
                              hipStream_t stream) {
  (void)in_sizes; (void)n_in; (void)out_size; (void)ws_size;
  const float* X  = (const float*)d_in[0];
  const float* Wq = (const float*)d_in[1];
  const float* bq = (const float*)d_in[2];
  const float* Wk = (const float*)d_in[3];
  const float* bk = (const float*)d_in[4];
  const float* Wv = (const float*)d_in[5];
  const float* bv = (const float*)d_in[6];
  float* out = (float*)d_out;

  // workspace layout (bf16 elements): Xb, Wt, Q (pre-scaled), K, Vt  (~66 MB)
  __bf16* Xb = (__bf16*)d_ws;                  // 16384*512
  __bf16* Wt = Xb + (long)MROWS * HID;         // 3*512*512, [g][out][in]
  __bf16* Q  = Wt + 3 * HID * HID;             // 16384*512 (pre-scaled)
  __bf16* Kb = Q + (long)MROWS * HID;          // 16384*512
  __bf16* Vt = Kb + (long)MROWS * HID;         // [b][512][4096]

  prep_x_kernel<<<(MROWS * HID) / 1024, 256, 0, stream>>>(X, Xb);
  prep_w_kernel<<<(3 * HID * HID) / 256, 256, 0, stream>>>(Wq, Wk, Wv, Wt);

  // fused QKV projection: M=16384, N=1536, K=512
  gemm_bt<MODE_QKV, 128, 128><<<dim3(12, 128, 1), 256, 0, stream>>>(
      Xb, Wt, Q, Kb, Vt, bq, bk, bv, nullptr,
      HID, HID, HID, HID, 0, 0, 0, 0);

  // fused softmax(QK^T)V: 256 blocks (1/CU), 16 waves, 64-row Q-tiles
  flash_attn<<<dim3(256), 1024, 0, stream>>>(Q, Kb, Vt, out);
}